// Round 1
// baseline (655.533 us; speedup 1.0000x reference)
//
#include <hip/hip_runtime.h>

#define B_ 32
#define C_ 128
#define H_ 64
#define W_ 64
#define HW_ (H_*W_)
#define EPS_ 1e-5f

// Stage pw^T so the GEMM can read pwT[c][o..o+7] contiguously.
__global__ __launch_bounds__(256) void transpose_pw(const float* __restrict__ pw1,
                                                    const float* __restrict__ pw2,
                                                    float* __restrict__ pwT1,
                                                    float* __restrict__ pwT2) {
    int t = threadIdx.x;
    for (int i = t; i < C_ * C_; i += 256) {
        int o = i >> 7;
        int c = i & (C_ - 1);
        pwT1[c * C_ + o] = pw1[i];
        pwT2[c * C_ + o] = pw2[i];
    }
}

// One workgroup per (n, h) row. Phase 1: (optional BN-on-read) + relu +
// depthwise 3x3 -> LDS[128][64]. Phase 2: pointwise 128x128 GEMM,
// 8o x 4p register micro-tile per thread, write pre-BN y.
__global__ __launch_bounds__(256) void fused_block(
    const float* __restrict__ xin,
    const float* __restrict__ scale_in,   // nullptr for block 1
    const float* __restrict__ shift_in,
    const float* __restrict__ dww,        // [C,9]
    const float* __restrict__ pwT,        // [C][O]
    float* __restrict__ yout)             // [B,O,H,W] pre-BN
{
    __shared__ float lds_dw[C_][W_];      // 32 KiB

    const int wg = blockIdx.x;
    const int n  = wg >> 6;
    const int h  = wg & (H_ - 1);
    const int t  = threadIdx.x;
    const int w  = t & (W_ - 1);
    const int c0 = t >> 6;

    const float* xb = xin + (size_t)n * C_ * HW_;
    const bool has_bn = (scale_in != nullptr);

    for (int c = c0; c < C_; c += 4) {
        const float* xc = xb + (size_t)c * HW_;
        const float sc = has_bn ? scale_in[c] : 1.f;
        const float sh = has_bn ? shift_in[c] : 0.f;
        const float* wc = dww + c * 9;
        float acc = 0.f;
        #pragma unroll
        for (int ky = 0; ky < 3; ky++) {
            int hy = h + ky - 1;
            if (hy < 0 || hy >= H_) continue;
            #pragma unroll
            for (int kx = 0; kx < 3; kx++) {
                int wx = w + kx - 1;
                if (wx < 0 || wx >= W_) continue;
                float v = fmaxf(fmaf(xc[hy * W_ + wx], sc, sh), 0.f);
                acc = fmaf(wc[ky * 3 + kx], v, acc);
            }
        }
        lds_dw[c][w] = acc;
    }
    __syncthreads();

    const int p0 = (t & 15) << 2;   // pixel start (0..60 step 4)
    const int o0 = (t >> 4) << 3;   // out-channel start (0..120 step 8)

    float acc[8][4];
    #pragma unroll
    for (int i = 0; i < 8; i++)
        #pragma unroll
        for (int j = 0; j < 4; j++) acc[i][j] = 0.f;

    for (int c = 0; c < C_; c++) {
        float4 d  = *(const float4*)&lds_dw[c][p0];
        float4 wa = *(const float4*)&pwT[c * C_ + o0];
        float4 wb = *(const float4*)&pwT[c * C_ + o0 + 4];
        float dv[4] = {d.x, d.y, d.z, d.w};
        float wv[8] = {wa.x, wa.y, wa.z, wa.w, wb.x, wb.y, wb.z, wb.w};
        #pragma unroll
        for (int i = 0; i < 8; i++)
            #pragma unroll
            for (int j = 0; j < 4; j++)
                acc[i][j] = fmaf(wv[i], dv[j], acc[i][j]);
    }

    float* yb = yout + (size_t)n * C_ * HW_ + h * W_;
    #pragma unroll
    for (int i = 0; i < 8; i++) {
        float4 v = make_float4(acc[i][0], acc[i][1], acc[i][2], acc[i][3]);
        *(float4*)&yb[(size_t)(o0 + i) * HW_ + p0] = v;
    }
}

// One workgroup per channel: biased batch stats over (N,H,W) -> scale/shift.
__global__ __launch_bounds__(256) void stats_bn(const float* __restrict__ y,
                                                const float* __restrict__ gamma,
                                                const float* __restrict__ beta,
                                                float* __restrict__ scale,
                                                float* __restrict__ shift) {
    const int c = blockIdx.x;
    const int t = threadIdx.x;
    float s = 0.f, ss = 0.f;
    const int total4 = B_ * HW_ / 4;           // 32768 float4 per channel
    for (int i = t; i < total4; i += 256) {
        int n = i >> 10;                        // 1024 float4 per (n,c) plane
        int p = i & 1023;
        const float4 v = *(const float4*)&y[((size_t)n * C_ + c) * HW_ + (size_t)p * 4];
        s  += v.x + v.y + v.z + v.w;
        ss  = fmaf(v.x, v.x, ss);
        ss  = fmaf(v.y, v.y, ss);
        ss  = fmaf(v.z, v.z, ss);
        ss  = fmaf(v.w, v.w, ss);
    }
    #pragma unroll
    for (int off = 32; off > 0; off >>= 1) {
        s  += __shfl_down(s, off);
        ss += __shfl_down(ss, off);
    }
    __shared__ float rs[4], rss[4];
    const int wid = t >> 6;
    if ((t & 63) == 0) { rs[wid] = s; rss[wid] = ss; }
    __syncthreads();
    if (t == 0) {
        float S  = rs[0] + rs[1] + rs[2] + rs[3];
        float SS = rss[0] + rss[1] + rss[2] + rss[3];
        const float inv = 1.f / (float)(B_ * HW_);
        float mean = S * inv;
        float var  = SS * inv - mean * mean;
        float sc   = gamma[c] * rsqrtf(var + EPS_);
        scale[c] = sc;
        shift[c] = fmaf(-mean, sc, beta[c]);
    }
}

// In-place BN apply on y2 (= d_out).
__global__ __launch_bounds__(256) void apply_bn(float* __restrict__ y,
                                                const float* __restrict__ scale,
                                                const float* __restrict__ shift) {
    const size_t total4 = (size_t)B_ * C_ * HW_ / 4;
    const size_t stride = (size_t)gridDim.x * 256;
    for (size_t i = (size_t)blockIdx.x * 256 + threadIdx.x; i < total4; i += stride) {
        int c = (int)((i >> 10) & (C_ - 1));   // (i*4 / 4096) % 128
        float sc = scale[c], sh = shift[c];
        float4 v = ((float4*)y)[i];
        v.x = fmaf(v.x, sc, sh);
        v.y = fmaf(v.y, sc, sh);
        v.z = fmaf(v.z, sc, sh);
        v.w = fmaf(v.w, sc, sh);
        ((float4*)y)[i] = v;
    }
}

extern "C" void kernel_launch(void* const* d_in, const int* in_sizes, int n_in,
                              void* d_out, int out_size, void* d_ws, size_t ws_size,
                              hipStream_t stream) {
    const float* x      = (const float*)d_in[0];
    const float* dw1    = (const float*)d_in[1];
    const float* pw1    = (const float*)d_in[2];
    const float* gamma1 = (const float*)d_in[3];
    const float* beta1  = (const float*)d_in[4];
    const float* dw2    = (const float*)d_in[5];
    const float* pw2    = (const float*)d_in[6];
    const float* gamma2 = (const float*)d_in[7];
    const float* beta2  = (const float*)d_in[8];
    float* out = (float*)d_out;
    float* ws  = (float*)d_ws;

    float* pwT1   = ws;                 // 16384
    float* pwT2   = ws + 16384;         // 16384
    float* scale1 = ws + 32768;         // 128
    float* shift1 = scale1 + 128;
    float* scale2 = shift1 + 128;
    float* shift2 = scale2 + 128;
    float* y1     = ws + 40960;         // 16777216 floats (64 MiB)

    transpose_pw<<<1, 256, 0, stream>>>(pw1, pw2, pwT1, pwT2);
    fused_block<<<B_ * H_, 256, 0, stream>>>(x, nullptr, nullptr, dw1, pwT1, y1);
    stats_bn<<<C_, 256, 0, stream>>>(y1, gamma1, beta1, scale1, shift1);
    fused_block<<<B_ * H_, 256, 0, stream>>>(y1, scale1, shift1, dw2, pwT2, out);
    stats_bn<<<C_, 256, 0, stream>>>(out, gamma2, beta2, scale2, shift2);
    apply_bn<<<4096, 256, 0, stream>>>(out, scale2, shift2);
}

// Round 2
// 376.713 us; speedup vs baseline: 1.7401x; 1.7401x over previous
//
#include <hip/hip_runtime.h>

#define B_ 32
#define C_ 128
#define H_ 64
#define W_ 64
#define HW_ (H_*W_)
#define NWG_ (B_*H_)          // 2048 workgroups for fused kernels
#define EPS_ 1e-5f

typedef __attribute__((ext_vector_type(8))) short s8v;   // 8 bf16 (4 VGPRs)
typedef __attribute__((ext_vector_type(4))) float f4v;   // MFMA accumulator

__device__ __forceinline__ short f2bf(float f) {
    union { float f; unsigned u; } v; v.f = f;
    unsigned r = v.u + 0x7fffu + ((v.u >> 16) & 1u);     // RNE
    return (short)(r >> 16);
}

// Pack pw (layout [o][c], fp32) into exact A-fragment order, bf16:
// frag[((mt*4+kk)*64 + lane)*8 + j] = pw[o = mt*16+(lane&15)][c = kk*32+(lane>>4)*8+j]
__global__ __launch_bounds__(256) void prep_wfrag(const float* __restrict__ pw1,
                                                  const float* __restrict__ pw2,
                                                  short* __restrict__ f1,
                                                  short* __restrict__ f2) {
    int t = blockIdx.x * 256 + threadIdx.x;
    if (t >= 16384) return;
    int j    = t & 7;
    int lane = (t >> 3) & 63;
    int kk   = (t >> 9) & 3;
    int mt   = t >> 11;
    int o = mt * 16 + (lane & 15);
    int c = kk * 32 + (lane >> 4) * 8 + j;
    f1[t] = f2bf(pw1[o * C_ + c]);
    f2[t] = f2bf(pw2[o * C_ + c]);
}

// One WG per (n,h). Phase 1: (BN-on-read) + relu + depthwise3x3 -> bf16 LDS
// xT[p][c], XOR-swizzled. Phase 2: MFMA GEMM D[o][p] = pw x dw, fp32 out +
// fused per-channel partial stats.
__global__ __launch_bounds__(256) void fused_block(
    const float* __restrict__ xin,
    const float* __restrict__ scale_in,   // nullptr for block 1
    const float* __restrict__ shift_in,
    const float* __restrict__ dww,        // [C][9]
    const short* __restrict__ wfrag,      // pre-packed A-frags, bf16
    float* __restrict__ yout,             // pre-BN y
    float* __restrict__ psum,             // [C][NWG_]
    float* __restrict__ psq)              // [C][NWG_]
{
    __shared__ short xT[64 * 128];        // 16 KiB, row p (256B) x col c, swizzled

    const int wg   = blockIdx.x;
    const int n    = wg >> 6;
    const int h    = wg & (H_ - 1);
    const int t    = threadIdx.x;
    const int lane = t & 63;
    const int wv   = t >> 6;
    const bool has_bn = (scale_in != nullptr);
    const float* xb = xin + (size_t)n * C_ * HW_;

    // ---- phase 1: depthwise; wave wv covers channel-groups wv*4 .. wv*4+3 ----
    for (int gi = 0; gi < 4; ++gi) {
        const int cg = wv * 4 + gi;
        s8v v;
        #pragma unroll
        for (int cc = 0; cc < 8; ++cc) {
            const int c = cg * 8 + cc;
            const float* xc = xb + (size_t)c * HW_;
            float sc = 1.f, sh = 0.f;
            if (has_bn) { sc = scale_in[c]; sh = shift_in[c]; }
            float r0 = 0.f, r2 = 0.f;
            if (h > 0)      r0 = fmaxf(fmaf(xc[(h - 1) * W_ + lane], sc, sh), 0.f);
            float r1 =           fmaxf(fmaf(xc[h       * W_ + lane], sc, sh), 0.f);
            if (h < H_ - 1) r2 = fmaxf(fmaf(xc[(h + 1) * W_ + lane], sc, sh), 0.f);
            float l0 = __shfl_up(r0, 1),  l1 = __shfl_up(r1, 1),  l2 = __shfl_up(r2, 1);
            float q0 = __shfl_down(r0, 1), q1 = __shfl_down(r1, 1), q2 = __shfl_down(r2, 1);
            if (lane == 0)  { l0 = 0.f; l1 = 0.f; l2 = 0.f; }
            if (lane == 63) { q0 = 0.f; q1 = 0.f; q2 = 0.f; }
            const float* wc = dww + c * 9;
            float a;
            a = wc[0] * l0;
            a = fmaf(wc[1], r0, a); a = fmaf(wc[2], q0, a);
            a = fmaf(wc[3], l1, a); a = fmaf(wc[4], r1, a); a = fmaf(wc[5], q1, a);
            a = fmaf(wc[6], l2, a); a = fmaf(wc[7], r2, a); a = fmaf(wc[8], q2, a);
            v[cc] = f2bf(a);
        }
        // row = pixel(lane), byte-col = cg*16, swizzle byte ^= (row&7)<<4
        *(s8v*)((char*)xT + lane * 256 + ((cg * 16) ^ ((lane & 7) << 4))) = v;
    }
    __syncthreads();

    // ---- phase 2: GEMM. wave wv owns o-tiles mt0, mt0+1 (32 o-rows) x all 64 p ----
    const int mt0 = wv * 2;
    f4v acc[2][4];
    #pragma unroll
    for (int m = 0; m < 2; ++m)
        #pragma unroll
        for (int nt = 0; nt < 4; ++nt)
            acc[m][nt] = (f4v)(0.f);

    #pragma unroll
    for (int kk = 0; kk < 4; ++kk) {
        s8v a0 = *(const s8v*)&wfrag[(((mt0    ) * 4 + kk) * 64 + lane) * 8];
        s8v a1 = *(const s8v*)&wfrag[(((mt0 + 1) * 4 + kk) * 64 + lane) * 8];
        #pragma unroll
        for (int nt = 0; nt < 4; ++nt) {
            const int p = nt * 16 + (lane & 15);
            const int colb = ((kk * 64) + ((lane >> 4) * 16)) ^ ((p & 7) << 4);
            s8v b = *(const s8v*)((char*)xT + p * 256 + colb);
            acc[0][nt] = __builtin_amdgcn_mfma_f32_16x16x32_bf16(a0, b, acc[0][nt], 0, 0, 0);
            acc[1][nt] = __builtin_amdgcn_mfma_f32_16x16x32_bf16(a1, b, acc[1][nt], 0, 0, 0);
        }
    }

    // ---- epilogue: store pre-BN y + fused partial stats ----
    float* yb = yout + (size_t)n * C_ * HW_ + h * W_;
    #pragma unroll
    for (int m = 0; m < 2; ++m) {
        #pragma unroll
        for (int r = 0; r < 4; ++r) {
            const int o = (mt0 + m) * 16 + (lane >> 4) * 4 + r;
            float s = 0.f, q = 0.f;
            #pragma unroll
            for (int nt = 0; nt < 4; ++nt) {
                const float val = acc[m][nt][r];
                yb[(size_t)o * HW_ + nt * 16 + (lane & 15)] = val;
                s += val; q = fmaf(val, val, q);
            }
            s += __shfl_xor(s, 1); q += __shfl_xor(q, 1);
            s += __shfl_xor(s, 2); q += __shfl_xor(q, 2);
            s += __shfl_xor(s, 4); q += __shfl_xor(q, 4);
            s += __shfl_xor(s, 8); q += __shfl_xor(q, 8);
            if ((lane & 15) == 0) {
                psum[o * NWG_ + wg] = s;
                psq [o * NWG_ + wg] = q;
            }
        }
    }
}

// One WG per channel: reduce 2048 partials -> scale/shift.
__global__ __launch_bounds__(256) void stats_reduce(const float* __restrict__ psum,
                                                    const float* __restrict__ psq,
                                                    const float* __restrict__ gamma,
                                                    const float* __restrict__ beta,
                                                    float* __restrict__ scale,
                                                    float* __restrict__ shift) {
    const int o = blockIdx.x;
    const int t = threadIdx.x;
    float s = 0.f, q = 0.f;
    for (int i = t; i < NWG_; i += 256) {
        s += psum[o * NWG_ + i];
        q += psq [o * NWG_ + i];
    }
    #pragma unroll
    for (int off = 32; off > 0; off >>= 1) {
        s += __shfl_down(s, off);
        q += __shfl_down(q, off);
    }
    __shared__ float rs[4], rq[4];
    const int wid = t >> 6;
    if ((t & 63) == 0) { rs[wid] = s; rq[wid] = q; }
    __syncthreads();
    if (t == 0) {
        float S = rs[0] + rs[1] + rs[2] + rs[3];
        float Q = rq[0] + rq[1] + rq[2] + rq[3];
        const float inv = 1.f / (float)(B_ * HW_);
        float mean = S * inv;
        float var  = Q * inv - mean * mean;
        float sc   = gamma[o] * rsqrtf(var + EPS_);
        scale[o] = sc;
        shift[o] = fmaf(-mean, sc, beta[o]);
    }
}

// In-place BN apply on y2 (= d_out).
__global__ __launch_bounds__(256) void apply_bn(float* __restrict__ y,
                                                const float* __restrict__ scale,
                                                const float* __restrict__ shift) {
    const size_t total4 = (size_t)B_ * C_ * HW_ / 4;
    const size_t stride = (size_t)gridDim.x * 256;
    for (size_t i = (size_t)blockIdx.x * 256 + threadIdx.x; i < total4; i += stride) {
        int c = (int)((i >> 10) & (C_ - 1));
        float sc = scale[c], sh = shift[c];
        float4 v = ((float4*)y)[i];
        v.x = fmaf(v.x, sc, sh);
        v.y = fmaf(v.y, sc, sh);
        v.z = fmaf(v.z, sc, sh);
        v.w = fmaf(v.w, sc, sh);
        ((float4*)y)[i] = v;
    }
}

extern "C" void kernel_launch(void* const* d_in, const int* in_sizes, int n_in,
                              void* d_out, int out_size, void* d_ws, size_t ws_size,
                              hipStream_t stream) {
    const float* x      = (const float*)d_in[0];
    const float* dw1    = (const float*)d_in[1];
    const float* pw1    = (const float*)d_in[2];
    const float* gamma1 = (const float*)d_in[3];
    const float* beta1  = (const float*)d_in[4];
    const float* dw2    = (const float*)d_in[5];
    const float* pw2    = (const float*)d_in[6];
    const float* gamma2 = (const float*)d_in[7];
    const float* beta2  = (const float*)d_in[8];
    float* out = (float*)d_out;
    char*  ws  = (char*)d_ws;

    short* wf1    = (short*)(ws);                    // 32 KiB
    short* wf2    = (short*)(ws + 32768);            // 32 KiB
    float* scale1 = (float*)(ws + 65536);            // 512 B each
    float* shift1 = (float*)(ws + 66048);
    float* scale2 = (float*)(ws + 66560);
    float* shift2 = (float*)(ws + 67072);
    float* psum   = (float*)(ws + 67584);            // 1 MiB
    float* psq    = (float*)(ws + 67584 + 1048576);  // 1 MiB
    float* y1     = (float*)(ws + 67584 + 2097152);  // 64 MiB

    prep_wfrag<<<64, 256, 0, stream>>>(pw1, pw2, wf1, wf2);
    fused_block<<<NWG_, 256, 0, stream>>>(x, nullptr, nullptr, dw1, wf1, y1, psum, psq);
    stats_reduce<<<C_, 256, 0, stream>>>(psum, psq, gamma1, beta1, scale1, shift1);
    fused_block<<<NWG_, 256, 0, stream>>>(y1, scale1, shift1, dw2, wf2, out, psum, psq);
    stats_reduce<<<C_, 256, 0, stream>>>(psum, psq, gamma2, beta2, scale2, shift2);
    apply_bn<<<4096, 256, 0, stream>>>(out, scale2, shift2);
}

// Round 3
// 349.004 us; speedup vs baseline: 1.8783x; 1.0794x over previous
//
#include <hip/hip_runtime.h>

#define B_ 32
#define C_ 128
#define H_ 64
#define W_ 64
#define HW_ (H_*W_)
#define HBLK 4
#define NWG_ (B_*(H_/HBLK))   // 512 workgroups for fused kernels
#define EPS_ 1e-5f

typedef __attribute__((ext_vector_type(8))) short s8v;   // 8 bf16 (4 VGPRs)
typedef __attribute__((ext_vector_type(4))) float f4v;   // MFMA accumulator
typedef unsigned short u16;

__device__ __forceinline__ short f2bf(float f) {
    union { float f; unsigned u; } v; v.f = f;
    unsigned r = v.u + 0x7fffu + ((v.u >> 16) & 1u);     // RNE
    return (short)(r >> 16);
}
__device__ __forceinline__ float bf2f(u16 u) {
    union { unsigned u; float f; } v; v.u = ((unsigned)u) << 16; return v.f;
}

// Pack pw (layout [o][c], fp32) into exact A-fragment order, bf16:
// frag[((mt*4+kk)*64 + lane)*8 + j] = pw[o = mt*16+(lane&15)][c = kk*32+(lane>>4)*8+j]
__global__ __launch_bounds__(256) void prep_wfrag(const float* __restrict__ pw1,
                                                  const float* __restrict__ pw2,
                                                  short* __restrict__ f1,
                                                  short* __restrict__ f2) {
    int t = blockIdx.x * 256 + threadIdx.x;
    if (t >= 16384) return;
    int j    = t & 7;
    int lane = (t >> 3) & 63;
    int kk   = (t >> 9) & 3;
    int mt   = t >> 11;
    int o = mt * 16 + (lane & 15);
    int c = kk * 32 + (lane >> 4) * 8 + j;
    f1[t] = f2bf(pw1[o * C_ + c]);
    f2[t] = f2bf(pw2[o * C_ + c]);
}

// One WG per (n, 4-row slab). Phase 1: (BN-on-read) + relu + depthwise3x3 ->
// bf16 LDS xT[256 px][128 c], XOR-swizzled. Phase 2: MFMA GEMM 128o x 256p,
// bf16 y out (NCHW) + fused per-channel partial stats.
template<int BF16IN>
__global__ __launch_bounds__(512, 4) void fused_block(
    const void*  __restrict__ xin_,
    const float* __restrict__ scale_in,   // BN1 params (BF16IN=1 only)
    const float* __restrict__ shift_in,
    const float* __restrict__ dww,        // [C][9]
    const short* __restrict__ wfrag,      // pre-packed A-frags, bf16
    u16*         __restrict__ yout,       // pre-BN y, bf16 NCHW
    float*       __restrict__ psum,       // [C][NWG_]
    float*       __restrict__ psq)        // [C][NWG_]
{
    __shared__ short xT[256 * 128];       // 64 KiB: row p (256B) x col c, swizzled

    const int wg   = blockIdx.x;
    const int n    = wg >> 4;
    const int h0   = (wg & 15) * HBLK;
    const int t    = threadIdx.x;
    const int lane = t & 63;
    const int wv   = t >> 6;              // 8 waves
    const int r    = lane >> 4;           // row-in-slab 0..3
    const int q    = lane & 15;           // px quad 0..15
    const int p0   = r * 64 + q * 4;      // first pixel this lane produces

    // ---- phase 1: depthwise; wave wv owns channels wv*16 .. wv*16+15 ----
    for (int g = 0; g < 2; ++g) {
        const int c0 = wv * 16 + g * 8;
        s8v row0, row1, row2, row3;
        #pragma unroll
        for (int cc = 0; cc < 8; ++cc) {
            const int c = c0 + cc;
            float sc = 1.f, sh = 0.f;
            if (BF16IN) { sc = scale_in[c]; sh = shift_in[c]; }
            const float* wc = dww + c * 9;
            float4 v[3];
            #pragma unroll
            for (int k = 0; k < 3; ++k) {
                const int hin = h0 + r - 1 + k;
                float4 val = make_float4(0.f, 0.f, 0.f, 0.f);
                if (hin >= 0 && hin < H_) {
                    if (BF16IN) {
                        const u16* xc = (const u16*)xin_ + ((size_t)(n * C_ + c)) * HW_;
                        ushort4 u = *(const ushort4*)(xc + hin * W_ + q * 4);
                        val = make_float4(bf2f(u.x), bf2f(u.y), bf2f(u.z), bf2f(u.w));
                    } else {
                        const float* xc = (const float*)xin_ + ((size_t)(n * C_ + c)) * HW_;
                        val = *(const float4*)(xc + hin * W_ + q * 4);
                    }
                    val.x = fmaxf(fmaf(val.x, sc, sh), 0.f);
                    val.y = fmaxf(fmaf(val.y, sc, sh), 0.f);
                    val.z = fmaxf(fmaf(val.z, sc, sh), 0.f);
                    val.w = fmaxf(fmaf(val.w, sc, sh), 0.f);
                }
                v[k] = val;
            }
            float lf0 = __shfl_up(v[0].w, 1), lf1 = __shfl_up(v[1].w, 1), lf2 = __shfl_up(v[2].w, 1);
            float rt0 = __shfl_down(v[0].x, 1), rt1 = __shfl_down(v[1].x, 1), rt2 = __shfl_down(v[2].x, 1);
            if (q == 0)  { lf0 = 0.f; lf1 = 0.f; lf2 = 0.f; }
            if (q == 15) { rt0 = 0.f; rt1 = 0.f; rt2 = 0.f; }
            const float e0[6] = {lf0, v[0].x, v[0].y, v[0].z, v[0].w, rt0};
            const float e1[6] = {lf1, v[1].x, v[1].y, v[1].z, v[1].w, rt1};
            const float e2[6] = {lf2, v[2].x, v[2].y, v[2].z, v[2].w, rt2};
            #pragma unroll
            for (int j = 0; j < 4; ++j) {
                float a;
                a = wc[0] * e0[j];
                a = fmaf(wc[1], e0[j+1], a); a = fmaf(wc[2], e0[j+2], a);
                a = fmaf(wc[3], e1[j],   a); a = fmaf(wc[4], e1[j+1], a); a = fmaf(wc[5], e1[j+2], a);
                a = fmaf(wc[6], e2[j],   a); a = fmaf(wc[7], e2[j+1], a); a = fmaf(wc[8], e2[j+2], a);
                const short bv = f2bf(a);
                if (j == 0) row0[cc] = bv;
                else if (j == 1) row1[cc] = bv;
                else if (j == 2) row2[cc] = bv;
                else row3[cc] = bv;
            }
        }
        const int cb = c0 * 2;            // byte col, 16B-aligned
        *(s8v*)((char*)xT + (p0 + 0) * 256 + (cb ^ (((p0 + 0) & 7) << 4))) = row0;
        *(s8v*)((char*)xT + (p0 + 1) * 256 + (cb ^ (((p0 + 1) & 7) << 4))) = row1;
        *(s8v*)((char*)xT + (p0 + 2) * 256 + (cb ^ (((p0 + 2) & 7) << 4))) = row2;
        *(s8v*)((char*)xT + (p0 + 3) * 256 + (cb ^ (((p0 + 3) & 7) << 4))) = row3;
    }
    __syncthreads();

    // ---- phase 2: GEMM; wave wv owns o-tile wv (16 o-rows) x 256 px ----
    s8v a[4];
    #pragma unroll
    for (int kk = 0; kk < 4; ++kk)
        a[kk] = *(const s8v*)&wfrag[((wv * 4 + kk) * 64 + lane) * 8];

    f4v acc[16];
    #pragma unroll
    for (int nt = 0; nt < 16; ++nt) acc[nt] = (f4v)(0.f);

    #pragma unroll
    for (int nt = 0; nt < 16; ++nt) {
        const int p = nt * 16 + q;
        const int rowb = p * 256;
        const int sw = (p & 7) << 4;
        #pragma unroll
        for (int kk = 0; kk < 4; ++kk) {
            s8v b = *(const s8v*)((char*)xT + rowb + ((kk * 64 + r * 16) ^ sw));
            acc[nt] = __builtin_amdgcn_mfma_f32_16x16x32_bf16(a[kk], b, acc[nt], 0, 0, 0);
        }
    }

    // ---- epilogue: bf16 y store + fused partial stats ----
    u16* yb = yout + ((size_t)n * C_ + wv * 16) * HW_ + h0 * W_;
    #pragma unroll
    for (int ri = 0; ri < 4; ++ri) {
        const int ot = r * 4 + ri;        // o within tile
        float s = 0.f, qq = 0.f;
        #pragma unroll
        for (int nt = 0; nt < 16; ++nt) {
            const float val = acc[nt][ri];
            yb[(size_t)ot * HW_ + nt * 16 + q] = (u16)f2bf(val);
            s += val; qq = fmaf(val, val, qq);
        }
        s += __shfl_xor(s, 1); qq += __shfl_xor(qq, 1);
        s += __shfl_xor(s, 2); qq += __shfl_xor(qq, 2);
        s += __shfl_xor(s, 4); qq += __shfl_xor(qq, 4);
        s += __shfl_xor(s, 8); qq += __shfl_xor(qq, 8);
        if (q == 0) {
            const int og = wv * 16 + ot;
            psum[og * NWG_ + wg] = s;
            psq [og * NWG_ + wg] = qq;
        }
    }
}

// One WG per channel: reduce NWG_ partials -> scale/shift.
__global__ __launch_bounds__(256) void stats_reduce(const float* __restrict__ psum,
                                                    const float* __restrict__ psq,
                                                    const float* __restrict__ gamma,
                                                    const float* __restrict__ beta,
                                                    float* __restrict__ scale,
                                                    float* __restrict__ shift) {
    const int o = blockIdx.x;
    const int t = threadIdx.x;
    float s = 0.f, q = 0.f;
    for (int i = t; i < NWG_; i += 256) {
        s += psum[o * NWG_ + i];
        q += psq [o * NWG_ + i];
    }
    #pragma unroll
    for (int off = 32; off > 0; off >>= 1) {
        s += __shfl_down(s, off);
        q += __shfl_down(q, off);
    }
    __shared__ float rs[4], rq[4];
    const int wid = t >> 6;
    if ((t & 63) == 0) { rs[wid] = s; rq[wid] = q; }
    __syncthreads();
    if (t == 0) {
        float S = rs[0] + rs[1] + rs[2] + rs[3];
        float Q = rq[0] + rq[1] + rq[2] + rq[3];
        const float inv = 1.f / (float)(B_ * HW_);
        float mean = S * inv;
        float var  = Q * inv - mean * mean;
        float sc   = gamma[o] * rsqrtf(var + EPS_);
        scale[o] = sc;
        shift[o] = fmaf(-mean, sc, beta[o]);
    }
}

// BN apply: read bf16 y2, write fp32 out.
__global__ __launch_bounds__(256) void apply_bn(const u16* __restrict__ y,
                                                float* __restrict__ out,
                                                const float* __restrict__ scale,
                                                const float* __restrict__ shift) {
    const size_t total8 = (size_t)B_ * C_ * HW_ / 8;
    const size_t stride = (size_t)gridDim.x * 256;
    for (size_t i = (size_t)blockIdx.x * 256 + threadIdx.x; i < total8; i += stride) {
        const size_t e = i * 8;
        const int c = (int)((e >> 12) & (C_ - 1));
        const float sc = scale[c], sh = shift[c];
        s8v v = *(const s8v*)(y + e);
        float4 o1, o2;
        o1.x = fmaf(bf2f((u16)v[0]), sc, sh);
        o1.y = fmaf(bf2f((u16)v[1]), sc, sh);
        o1.z = fmaf(bf2f((u16)v[2]), sc, sh);
        o1.w = fmaf(bf2f((u16)v[3]), sc, sh);
        o2.x = fmaf(bf2f((u16)v[4]), sc, sh);
        o2.y = fmaf(bf2f((u16)v[5]), sc, sh);
        o2.z = fmaf(bf2f((u16)v[6]), sc, sh);
        o2.w = fmaf(bf2f((u16)v[7]), sc, sh);
        *(float4*)(out + e)     = o1;
        *(float4*)(out + e + 4) = o2;
    }
}

extern "C" void kernel_launch(void* const* d_in, const int* in_sizes, int n_in,
                              void* d_out, int out_size, void* d_ws, size_t ws_size,
                              hipStream_t stream) {
    const float* x      = (const float*)d_in[0];
    const float* dw1    = (const float*)d_in[1];
    const float* pw1    = (const float*)d_in[2];
    const float* gamma1 = (const float*)d_in[3];
    const float* beta1  = (const float*)d_in[4];
    const float* dw2    = (const float*)d_in[5];
    const float* pw2    = (const float*)d_in[6];
    const float* gamma2 = (const float*)d_in[7];
    const float* beta2  = (const float*)d_in[8];
    float* out = (float*)d_out;
    char*  ws  = (char*)d_ws;

    short* wf1    = (short*)(ws);                    // 32 KiB
    short* wf2    = (short*)(ws + 32768);            // 32 KiB
    float* scale1 = (float*)(ws + 65536);
    float* shift1 = (float*)(ws + 66048);
    float* scale2 = (float*)(ws + 66560);
    float* shift2 = (float*)(ws + 67072);
    float* psum   = (float*)(ws + 67584);            // 256 KiB
    float* psq    = (float*)(ws + 67584 + 262144);   // 256 KiB
    u16*   y1     = (u16*)(ws + 591872);             // 32 MiB bf16
    u16*   y2     = (u16*)(ws + 591872 + 33554432);  // 32 MiB bf16

    prep_wfrag<<<64, 256, 0, stream>>>(pw1, pw2, wf1, wf2);
    fused_block<0><<<NWG_, 512, 0, stream>>>(x, nullptr, nullptr, dw1, wf1, y1, psum, psq);
    stats_reduce<<<C_, 256, 0, stream>>>(psum, psq, gamma1, beta1, scale1, shift1);
    fused_block<1><<<NWG_, 512, 0, stream>>>(y1, scale1, shift1, dw2, wf2, y2, psum, psq);
    stats_reduce<<<C_, 256, 0, stream>>>(psum, psq, gamma2, beta2, scale2, shift2);
    apply_bn<<<2048, 256, 0, stream>>>(y2, out, scale2, shift2);
}